// Round 5
// baseline (187.499 us; speedup 1.0000x reference)
//
#include <hip/hip_runtime.h>
#include <hip/hip_bf16.h>

// Problem constants
#define B_  128
#define I_  64
#define P_  16
#define T_  5
#define NT  3
#define VOCAB 100000
#define D_  64
#define NROWS (NT * VOCAB)     // 300000
#define NPAIR (B_ * I_)        // 8192 (n)
#define OUTROWS NPAIR          // 8192 output rows of 64

// ---------- bf16 helpers ----------
__device__ __forceinline__ float b2f(unsigned short h) {
    return __uint_as_float(((unsigned int)h) << 16);
}
__device__ __forceinline__ unsigned short f2b(float f) {
    unsigned int u = __float_as_uint(f);
    return (unsigned short)((u + 0x7fffu + ((u >> 16) & 1u)) >> 16);   // RNE
}
__device__ __forceinline__ float pkLo(unsigned int x) {      // low bf16 -> f32
    return __uint_as_float(x << 16);
}
__device__ __forceinline__ float pkHi(unsigned int x) {      // high bf16 -> f32
    return __uint_as_float(x & 0xffff0000u);
}

typedef short short8 __attribute__((ext_vector_type(8)));
typedef float f32x4 __attribute__((ext_vector_type(4)));

// =====================================================================
// Phase 1: UV[r][c]: c<64 -> T[r,:]·W0[c,:] ; c>=64 -> T[r,:]·W1[c-64,:]
// m97-style async staging: global_load_lds (16B) stages 64-row groups of
// the fp32 table into LDS, TRANSPOSED chunk-major so fragment ds_reads
// are 2-way-conflict-free (free). Zero VGPRs spent on staging -> no
// spill/sink fights (R2/R3 lesson). 4 blocks/CU x 16KB in flight = BW-
// saturating. Weights-first MFMA (D rows = channels) -> 8B stores.
// =====================================================================
#define LDB 72            // padded row stride for weight tile (bf16)
#define GRP_PER_BLK 2     // 64-row groups per block
__global__ __launch_bounds__(256) void transform_tables(
        const float* __restrict__ tables, const float* __restrict__ convw,
        unsigned short* __restrict__ UV) {
    __shared__ unsigned short Bt[128 * LDB];          // 18432 B
    __shared__ __align__(16) float Abuf[16 * 256];    // chunk-major: [c][row][4f] 16384 B
    const int tid = threadIdx.x;

    // Bt[c][i]: c<64 -> W[c][i][0], c>=64 -> W[c-64][i][1]
    {
        int c = tid >> 1, half = tid & 1;
        const float* wp = (c < 64) ? (convw + c * 128) : (convw + (c - 64) * 128 + 1);
#pragma unroll
        for (int k = 0; k < 32; ++k) {
            int i = half * 32 + k;
            Bt[c * LDB + i] = f2b(wp[i * 2]);
        }
    }

    const int w = tid >> 6;          // wave 0..3
    const int lane = tid & 63;
    const int l16 = lane & 15;
    const int quad = lane >> 4;

    for (int g = 0; g < GRP_PER_BLK; ++g) {
        const int gr0 = (blockIdx.x * GRP_PER_BLK + g) * 64;
        // lane's source row for staging (clamped; stores are guarded below)
        int grow = gr0 + lane;
        if (grow >= NROWS) grow = NROWS - 1;

        __syncthreads();   // prev compute done reading Abuf / Bt ready (g==0)

        // wave w stages chunks w*4 .. w*4+3: instruction c puts float4-chunk c
        // of all 64 rows at Abuf[c*256 + lane*4]  (wave-uniform base + lane*16B)
#pragma unroll
        for (int c2 = 0; c2 < 4; ++c2) {
            int c = w * 4 + c2;
            const float* gp = tables + (size_t)grow * 64 + c * 4;
            __builtin_amdgcn_global_load_lds(
                (const __attribute__((address_space(1))) void*)gp,
                (__attribute__((address_space(3))) void*)&Abuf[c * 256],
                16, 0, 0);
        }
        __syncthreads();   // staging complete (vmcnt drain at barrier)

        // my tile: rows gr0 + w*16 + l16 ; A-frag k = quad*8+j -> chunks quad*2, quad*2+1
        const int rig = w * 16 + l16;
        float4 f0 = *(const float4*)&Abuf[(quad * 2 + 0) * 256 + rig * 4];
        float4 f1 = *(const float4*)&Abuf[(quad * 2 + 1) * 256 + rig * 4];
        float4 f2 = *(const float4*)&Abuf[(8 + quad * 2 + 0) * 256 + rig * 4];
        float4 f3 = *(const float4*)&Abuf[(8 + quad * 2 + 1) * 256 + rig * 4];
        short8 a0, a1;
        a0[0] = (short)f2b(f0.x); a0[1] = (short)f2b(f0.y);
        a0[2] = (short)f2b(f0.z); a0[3] = (short)f2b(f0.w);
        a0[4] = (short)f2b(f1.x); a0[5] = (short)f2b(f1.y);
        a0[6] = (short)f2b(f1.z); a0[7] = (short)f2b(f1.w);
        a1[0] = (short)f2b(f2.x); a1[1] = (short)f2b(f2.y);
        a1[2] = (short)f2b(f2.z); a1[3] = (short)f2b(f2.w);
        a1[4] = (short)f2b(f3.x); a1[5] = (short)f2b(f3.y);
        a1[6] = (short)f2b(f3.z); a1[7] = (short)f2b(f3.w);

        f32x4 acc[8];
#pragma unroll
        for (int ns = 0; ns < 8; ++ns) acc[ns] = (f32x4){0.f, 0.f, 0.f, 0.f};
#pragma unroll
        for (int ns = 0; ns < 8; ++ns) {
            short8 b0 = *(const short8*)&Bt[(ns * 16 + l16) * LDB + quad * 8];
            short8 b1 = *(const short8*)&Bt[(ns * 16 + l16) * LDB + 32 + quad * 8];
            acc[ns] = __builtin_amdgcn_mfma_f32_16x16x32_bf16(b0, a0, acc[ns], 0, 0, 0);
            acc[ns] = __builtin_amdgcn_mfma_f32_16x16x32_bf16(b1, a1, acc[ns], 0, 0, 0);
        }
        // D layout: col(l16)=table row, row(quad*4+j)=channel -> 8B stores
        const int row = gr0 + rig;
        if (row < NROWS) {
            unsigned short* op = UV + (size_t)row * 128 + quad * 4;
#pragma unroll
            for (int ns = 0; ns < 8; ++ns) {
                unsigned long long pk =
                      (unsigned long long)f2b(acc[ns][0])
                    | ((unsigned long long)f2b(acc[ns][1]) << 16)
                    | ((unsigned long long)f2b(acc[ns][2]) << 32)
                    | ((unsigned long long)f2b(acc[ns][3]) << 48);
                *(unsigned long long*)(op + ns * 16) = pk;
            }
        }
    }
}

// =====================================================================
// Phase 2: final[nn,d] = b[d] + max_{pp,to} ( U[r_to,d] + V[r_{t+1},d] )
// Paired-gather (one dword serves two row-gathers across wave halves),
// FULL unroll (16 pp) to maximize outstanding loads.
// =====================================================================
__global__ __launch_bounds__(256) void gather_max(
        const int* __restrict__ path_input, const int* __restrict__ path_type,
        const unsigned int* __restrict__ UVu, const float* __restrict__ bias,
        float* __restrict__ out) {
    __shared__ int ridx[4][16][5];   // row * 64 (uint offsets)
    const int tid = threadIdx.x;
    const int nn0 = blockIdx.x * 4;
    for (int i = tid; i < 320; i += 256) {
        int ln = i / 80, j = i - ln * 80;
        int pp = j / 5, t = j - pp * 5;
        int nn = nn0 + ln;
        int g = nn >> 4, q = nn & 15;
        int addr = ((pp * 512 + g) * 16 + q) * 5 + t;
        ridx[ln][pp][t] = (path_type[t] * VOCAB + path_input[addr]) * 64;
    }
    __syncthreads();

    const int w = tid >> 6, lane = tid & 63;
    const int half = lane >> 5, l = lane & 31;
    const int nn = nn0 + w;

    float accLo = -1e30f, accHi = -1e30f;
#pragma unroll
    for (int pp = 0; pp < 16; ++pp) {
        int r0 = ridx[w][pp][0];
        int r1 = ridx[w][pp][1];
        int r2 = ridx[w][pp][2];
        int r3 = ridx[w][pp][3];
        int r4 = ridx[w][pp][4];
        unsigned int xa = UVu[(half ? r1 : r0) + l];          // {u0 | u1}
        unsigned int xb = UVu[(half ? r3 : r2) + l];          // {u2 | u3}
        unsigned int xc = UVu[(half ? r2 : r1) + 32 + l];     // {v1 | v2}
        unsigned int xd = UVu[(half ? r4 : r3) + 32 + l];     // {v3 | v4}
        float s1Lo = pkLo(xa) + pkLo(xc);
        float s1Hi = pkHi(xa) + pkHi(xc);
        float s2Lo = pkLo(xb) + pkLo(xd);
        float s2Hi = pkHi(xb) + pkHi(xd);
        accLo = fmaxf(accLo, fmaxf(s1Lo, s2Lo));
        accHi = fmaxf(accHi, fmaxf(s1Hi, s2Hi));
    }
    float oLo = fmaxf(accLo, __shfl_xor(accLo, 32));
    float oHi = fmaxf(accHi, __shfl_xor(accHi, 32));
    if (half == 0) {
        float2 bv = *(const float2*)(bias + 2 * l);
        float2 o;
        o.x = oLo + bv.x;
        o.y = oHi + bv.y;
        *(float2*)(out + (size_t)nn * 64 + 2 * l) = o;
    }
}

// =====================================================================
// Fallback (if workspace too small): direct fused fp32.
// =====================================================================
__global__ __launch_bounds__(64) void fused_direct(
        const int* __restrict__ path_input, const int* __restrict__ path_type,
        const float* __restrict__ tables, const float* __restrict__ convw,
        const float* __restrict__ bias, float* __restrict__ out) {
    const int nn = blockIdx.x;
    const int o = threadIdx.x;
    const int g = nn >> 4;
    const int q = nn & 15;
    float w0[64], w1[64];
#pragma unroll
    for (int i = 0; i < 64; ++i) {
        w0[i] = convw[o * 128 + i * 2];
        w1[i] = convw[o * 128 + i * 2 + 1];
    }
    int tb[5];
#pragma unroll
    for (int t = 0; t < 5; ++t) tb[t] = path_type[t] * VOCAB;
    __shared__ float emb[5][64];
    float acc = -1e30f;
    for (int pp = 0; pp < 16; ++pp) {
        int m = pp * 512 + g;
        const int* ip = path_input + ((m * 16 + q) * 5);
        __syncthreads();
#pragma unroll
        for (int t = 0; t < 5; ++t)
            emb[t][o] = tables[(size_t)(tb[t] + ip[t]) * 64 + o];
        __syncthreads();
#pragma unroll
        for (int to = 0; to < 4; ++to) {
            float s = 0.f;
#pragma unroll
            for (int i = 0; i < 64; ++i)
                s += w0[i] * emb[to][i] + w1[i] * emb[to + 1][i];
            acc = fmaxf(acc, s);
        }
    }
    out[(size_t)nn * 64 + o] = acc + bias[o];
}

extern "C" void kernel_launch(void* const* d_in, const int* in_sizes, int n_in,
                              void* d_out, int out_size, void* d_ws, size_t ws_size,
                              hipStream_t stream) {
    const int*   path_input = (const int*)d_in[0];
    const int*   path_type  = (const int*)d_in[1];
    const float* tables     = (const float*)d_in[2];
    const float* convw      = (const float*)d_in[3];
    const float* convb      = (const float*)d_in[4];
    float* out = (float*)d_out;

    const size_t need = (size_t)NROWS * 128 * sizeof(unsigned short); // 76.8 MB
    if (ws_size >= need) {
        unsigned short* UV = (unsigned short*)d_ws;
        // 4688 groups of 64 rows, GRP_PER_BLK per block
        const int ngrp = (NROWS + 63) / 64;
        transform_tables<<<(ngrp + GRP_PER_BLK - 1) / GRP_PER_BLK, 256, 0, stream>>>(
            tables, convw, UV);
        gather_max<<<OUTROWS / 4, 256, 0, stream>>>(path_input, path_type,
                                                    (const unsigned int*)UV, convb, out);
    } else {
        fused_direct<<<OUTROWS, 64, 0, stream>>>(path_input, path_type, tables, convw, convb, out);
    }
}

// Round 6
// 183.948 us; speedup vs baseline: 1.0193x; 1.0193x over previous
//
#include <hip/hip_runtime.h>
#include <hip/hip_bf16.h>

// Problem constants
#define B_  128
#define I_  64
#define P_  16
#define T_  5
#define NT  3
#define VOCAB 100000
#define D_  64
#define NROWS (NT * VOCAB)     // 300000
#define NPAIR (B_ * I_)        // 8192 (n)
#define OUTROWS NPAIR          // 8192 output rows of 64

// ---------- bf16 helpers ----------
__device__ __forceinline__ float b2f(unsigned short h) {
    return __uint_as_float(((unsigned int)h) << 16);
}
__device__ __forceinline__ unsigned short f2b(float f) {
    unsigned int u = __float_as_uint(f);
    return (unsigned short)((u + 0x7fffu + ((u >> 16) & 1u)) >> 16);   // RNE
}
__device__ __forceinline__ float pkLo(unsigned int x) {      // low bf16 -> f32
    return __uint_as_float(x << 16);
}
__device__ __forceinline__ float pkHi(unsigned int x) {      // high bf16 -> f32
    return __uint_as_float(x & 0xffff0000u);
}

typedef short short8 __attribute__((ext_vector_type(8)));
typedef float f32x4 __attribute__((ext_vector_type(4)));

// =====================================================================
// Phase 1: UV[r][c]: c<64 -> T[r,:]·W0[c,:] ; c>=64 -> T[r,:]·W1[c-64,:]
// R3 structure (plain per-wave loads; async LDS staging regressed in R4
// due to barrier-drain serialization). Work split: 2 tiles/wave (was 4)
// -> 8 upfront float4 (32 VGPR, stays hoisted) and grid 1172->2344
// blocks: R3 was grid-capped at 18 waves/CU.
// =====================================================================
#define LDB 72   // padded row stride for weight tile (bf16 elems)
__global__ __launch_bounds__(256) void transform_tables(
        const float* __restrict__ tables, const float* __restrict__ convw,
        unsigned short* __restrict__ UV) {
    __shared__ unsigned short Bt[128 * LDB];   // 18432 B
    const int tid = threadIdx.x;

    // Bt[c][i]: c<64 -> W[c][i][0], c>=64 -> W[c-64][i][1]; convw[o*128+i*2+k]
    {
        int c = tid >> 1, half = tid & 1;
        const float* wp = (c < 64) ? (convw + c * 128) : (convw + (c - 64) * 128 + 1);
#pragma unroll
        for (int k = 0; k < 32; ++k) {
            int i = half * 32 + k;
            Bt[c * LDB + i] = f2b(wp[i * 2]);
        }
    }
    __syncthreads();

    const int w = __builtin_amdgcn_readfirstlane(tid >> 6);   // wave 0..3
    const int lane = tid & 63;
    const int l16 = lane & 15;
    const int quad = lane >> 4;
    const int base_tile = blockIdx.x * 8 + w * 2;   // 2 tiles/wave

    // ---- issue all 8 A loads upfront (2 tiles x 4 float4) ----
    float4 A[8];
#pragma unroll
    for (int t = 0; t < 2; ++t) {
        int row = (base_tile + t) * 16 + l16;
        int rowc = row < NROWS ? row : NROWS - 1;
        const float* ap = tables + (size_t)rowc * 64 + quad * 8;
        A[t * 4 + 0] = *(const float4*)(ap);
        A[t * 4 + 1] = *(const float4*)(ap + 4);
        A[t * 4 + 2] = *(const float4*)(ap + 32);
        A[t * 4 + 3] = *(const float4*)(ap + 36);
    }

#pragma unroll
    for (int t = 0; t < 2; ++t) {
        float4 fa = A[t * 4 + 0], fb = A[t * 4 + 1];
        float4 fc = A[t * 4 + 2], fd = A[t * 4 + 3];
        short8 a0, a1;
        a0[0] = (short)f2b(fa.x); a0[1] = (short)f2b(fa.y);
        a0[2] = (short)f2b(fa.z); a0[3] = (short)f2b(fa.w);
        a0[4] = (short)f2b(fb.x); a0[5] = (short)f2b(fb.y);
        a0[6] = (short)f2b(fb.z); a0[7] = (short)f2b(fb.w);
        a1[0] = (short)f2b(fc.x); a1[1] = (short)f2b(fc.y);
        a1[2] = (short)f2b(fc.z); a1[3] = (short)f2b(fc.w);
        a1[4] = (short)f2b(fd.x); a1[5] = (short)f2b(fd.y);
        a1[6] = (short)f2b(fd.z); a1[7] = (short)f2b(fd.w);

        f32x4 acc[8];
#pragma unroll
        for (int ns = 0; ns < 8; ++ns) acc[ns] = (f32x4){0.f, 0.f, 0.f, 0.f};
#pragma unroll
        for (int ns = 0; ns < 8; ++ns) {
            short8 b0 = *(const short8*)&Bt[(ns * 16 + l16) * LDB + quad * 8];
            short8 b1 = *(const short8*)&Bt[(ns * 16 + l16) * LDB + 32 + quad * 8];
            acc[ns] = __builtin_amdgcn_mfma_f32_16x16x32_bf16(b0, a0, acc[ns], 0, 0, 0);
            acc[ns] = __builtin_amdgcn_mfma_f32_16x16x32_bf16(b1, a1, acc[ns], 0, 0, 0);
        }
        // D layout: col(lane&15)=table row, row(quad*4+j)=channel -> 8B stores
        int row = (base_tile + t) * 16 + l16;
        if (row < NROWS) {
            unsigned short* op = UV + (size_t)row * 128 + quad * 4;
#pragma unroll
            for (int ns = 0; ns < 8; ++ns) {
                unsigned long long pk =
                      (unsigned long long)f2b(acc[ns][0])
                    | ((unsigned long long)f2b(acc[ns][1]) << 16)
                    | ((unsigned long long)f2b(acc[ns][2]) << 32)
                    | ((unsigned long long)f2b(acc[ns][3]) << 48);
                *(unsigned long long*)(op + ns * 16) = pk;
            }
        }
    }
}

// =====================================================================
// Phase 2: final[nn,d] = b[d] + max_{pp,to} ( U[r_to,d] + V[r_{t+1},d] )
// Paired-gather (one dword = two row-half gathers across wave halves).
// NEW: each nn is split across 2 waves (pp 0-7 / 8-15) -> half the VGPR
// pressure per wave and 2x wave-level parallelism; merge via LDS.
// Block = 256 thr = 4 waves = 2 nn. Grid 4096.
// =====================================================================
__global__ __launch_bounds__(256) void gather_max(
        const int* __restrict__ path_input, const int* __restrict__ path_type,
        const unsigned int* __restrict__ UVu, const float* __restrict__ bias,
        float* __restrict__ out) {
    __shared__ int ridx[2][16][5];        // row * 64 (uint offsets)
    __shared__ float part[2][2][64];      // [ln][pp-half][chan]
    const int tid = threadIdx.x;
    const int nn0 = blockIdx.x * 2;
    for (int i = tid; i < 160; i += 256) {
        int ln = i / 80, j = i - ln * 80;
        int pp = j / 5, t = j - pp * 5;
        int nn = nn0 + ln;
        int g = nn >> 4, q = nn & 15;
        int addr = ((pp * 512 + g) * 16 + q) * 5 + t;
        ridx[ln][pp][t] = (path_type[t] * VOCAB + path_input[addr]) * 64;
    }
    __syncthreads();

    const int w = __builtin_amdgcn_readfirstlane(tid >> 6);
    const int lane = tid & 63;
    const int half = lane >> 5, l = lane & 31;
    const int ln = w & 1;          // which nn
    const int ph = w >> 1;         // pp half: 0 -> pp 0..7, 1 -> pp 8..15

    float accLo = -1e30f, accHi = -1e30f;
#pragma unroll
    for (int k = 0; k < 8; ++k) {
        int pp = ph * 8 + k;
        int r0 = ridx[ln][pp][0];
        int r1 = ridx[ln][pp][1];
        int r2 = ridx[ln][pp][2];
        int r3 = ridx[ln][pp][3];
        int r4 = ridx[ln][pp][4];
        unsigned int xa = UVu[(half ? r1 : r0) + l];          // {u0 | u1}
        unsigned int xb = UVu[(half ? r3 : r2) + l];          // {u2 | u3}
        unsigned int xc = UVu[(half ? r2 : r1) + 32 + l];     // {v1 | v2}
        unsigned int xd = UVu[(half ? r4 : r3) + 32 + l];     // {v3 | v4}
        float s1Lo = pkLo(xa) + pkLo(xc);
        float s1Hi = pkHi(xa) + pkHi(xc);
        float s2Lo = pkLo(xb) + pkLo(xd);
        float s2Hi = pkHi(xb) + pkHi(xd);
        accLo = fmaxf(accLo, fmaxf(s1Lo, s2Lo));
        accHi = fmaxf(accHi, fmaxf(s1Hi, s2Hi));
    }
    // merge the two wave-halves' window terms (channels interleaved 2l/2l+1)
    float oLo = fmaxf(accLo, __shfl_xor(accLo, 32));
    float oHi = fmaxf(accHi, __shfl_xor(accHi, 32));
    if (half == 0) {
        part[ln][ph][2 * l]     = oLo;
        part[ln][ph][2 * l + 1] = oHi;
    }
    __syncthreads();
    if (tid < 128) {
        int oln = tid >> 6, c = tid & 63;
        float v = fmaxf(part[oln][0][c], part[oln][1][c]) + bias[c];
        out[(size_t)(nn0 + oln) * 64 + c] = v;
    }
}

// =====================================================================
// Fallback (if workspace too small): direct fused fp32.
// =====================================================================
__global__ __launch_bounds__(64) void fused_direct(
        const int* __restrict__ path_input, const int* __restrict__ path_type,
        const float* __restrict__ tables, const float* __restrict__ convw,
        const float* __restrict__ bias, float* __restrict__ out) {
    const int nn = blockIdx.x;
    const int o = threadIdx.x;
    const int g = nn >> 4;
    const int q = nn & 15;
    float w0[64], w1[64];
#pragma unroll
    for (int i = 0; i < 64; ++i) {
        w0[i] = convw[o * 128 + i * 2];
        w1[i] = convw[o * 128 + i * 2 + 1];
    }
    int tb[5];
#pragma unroll
    for (int t = 0; t < 5; ++t) tb[t] = path_type[t] * VOCAB;
    __shared__ float emb[5][64];
    float acc = -1e30f;
    for (int pp = 0; pp < 16; ++pp) {
        int m = pp * 512 + g;
        const int* ip = path_input + ((m * 16 + q) * 5);
        __syncthreads();
#pragma unroll
        for (int t = 0; t < 5; ++t)
            emb[t][o] = tables[(size_t)(tb[t] + ip[t]) * 64 + o];
        __syncthreads();
#pragma unroll
        for (int to = 0; to < 4; ++to) {
            float s = 0.f;
#pragma unroll
            for (int i = 0; i < 64; ++i)
                s += w0[i] * emb[to][i] + w1[i] * emb[to + 1][i];
            acc = fmaxf(acc, s);
        }
    }
    out[(size_t)nn * 64 + o] = acc + bias[o];
}

extern "C" void kernel_launch(void* const* d_in, const int* in_sizes, int n_in,
                              void* d_out, int out_size, void* d_ws, size_t ws_size,
                              hipStream_t stream) {
    const int*   path_input = (const int*)d_in[0];
    const int*   path_type  = (const int*)d_in[1];
    const float* tables     = (const float*)d_in[2];
    const float* convw      = (const float*)d_in[3];
    const float* convb      = (const float*)d_in[4];
    float* out = (float*)d_out;

    const size_t need = (size_t)NROWS * 128 * sizeof(unsigned short); // 76.8 MB
    if (ws_size >= need) {
        unsigned short* UV = (unsigned short*)d_ws;
        // 18750 tiles, 8 per block -> 2344 blocks
        transform_tables<<<2344, 256, 0, stream>>>(tables, convw, UV);
        gather_max<<<OUTROWS / 2, 256, 0, stream>>>(path_input, path_type,
                                                    (const unsigned int*)UV, convb, out);
    } else {
        fused_direct<<<OUTROWS, 64, 0, stream>>>(path_input, path_type, tables, convw, convb, out);
    }
}

// Round 7
// 168.425 us; speedup vs baseline: 1.1132x; 1.0922x over previous
//
#include <hip/hip_runtime.h>
#include <hip/hip_bf16.h>

// Problem constants
#define B_  128
#define I_  64
#define P_  16
#define T_  5
#define NT  3
#define VOCAB 100000
#define D_  64
#define NROWS (NT * VOCAB)     // 300000
#define NPAIR (B_ * I_)        // 8192 (n)
#define OUTROWS NPAIR          // 8192 output rows of 64
#define NTILES ((NROWS + 15) / 16)   // 18750

// ---------- bf16 helpers ----------
__device__ __forceinline__ float b2f(unsigned short h) {
    return __uint_as_float(((unsigned int)h) << 16);
}
__device__ __forceinline__ unsigned short f2b(float f) {
    unsigned int u = __float_as_uint(f);
    return (unsigned short)((u + 0x7fffu + ((u >> 16) & 1u)) >> 16);   // RNE
}
__device__ __forceinline__ float pkLo(unsigned int x) {      // low bf16 -> f32
    return __uint_as_float(x << 16);
}
__device__ __forceinline__ float pkHi(unsigned int x) {      // high bf16 -> f32
    return __uint_as_float(x & 0xffff0000u);
}

typedef short short8 __attribute__((ext_vector_type(8)));
typedef float f32x4 __attribute__((ext_vector_type(4)));

// =====================================================================
// wprep: write bf16 weight fragments to ws in EXACT mfma first-operand
// lane order. Entry e = ((cb*2+half)*4+quad)*16 + m holds 8 shorts:
//   channel c = cb*16+m, k = half*32 + quad*8 + j
//   c<64 -> W0[c][k] = convw[c*128 + 2k] ; else W1[c-64][k] = convw[..+1]
// A wave reading fragment (cb,half) loads lane-contiguous 16B chunks.
// =====================================================================
__global__ __launch_bounds__(256) void wprep(
        const float* __restrict__ convw, unsigned short* __restrict__ Wf) {
    const int e0 = threadIdx.x * 4;
#pragma unroll
    for (int e = e0; e < e0 + 4; ++e) {
        int m = e & 15;
        int quad = (e >> 4) & 3;
        int half = (e >> 6) & 1;
        int cb = e >> 7;
        int c = cb * 16 + m;
        const float* wp = (c < 64) ? (convw + c * 128) : (convw + (c - 64) * 128 + 1);
#pragma unroll
        for (int j = 0; j < 8; ++j) {
            int k = half * 32 + quad * 8 + j;
            Wf[e * 8 + j] = f2b(wp[k * 2]);
        }
    }
}

// =====================================================================
// Phase 1: UV[r][c]: c<64 -> T[r,:]·W0[c,:] ; c>=64 -> T[r,:]·W1[c-64,:]
// LDS-FREE, BARRIER-FREE: weight fragments loaded from the 16KB Wf
// buffer (L1-resident after first tile) as coalesced 16B global loads.
// One 16-row tile per wave; nothing blocks cross-wave overlap.
// =====================================================================
__global__ __launch_bounds__(256) void transform_tables(
        const float* __restrict__ tables, const unsigned short* __restrict__ Wf,
        unsigned short* __restrict__ UV) {
    const int tid = threadIdx.x;
    const int w = tid >> 6;
    const int lane = tid & 63;
    const int l16 = lane & 15;
    const int quad = lane >> 4;

    const int tile = blockIdx.x * 4 + w;
    if (tile >= NTILES) return;
    const int row = tile * 16 + l16;      // < NROWS since NROWS % 16 == 0

    // ---- table row loads (4 x 16B) ----
    const float* ap = tables + (size_t)row * 64 + quad * 8;
    float4 f0 = *(const float4*)(ap);
    float4 f1 = *(const float4*)(ap + 4);
    float4 f2 = *(const float4*)(ap + 32);
    float4 f3 = *(const float4*)(ap + 36);
    short8 a0, a1;
    a0[0] = (short)f2b(f0.x); a0[1] = (short)f2b(f0.y);
    a0[2] = (short)f2b(f0.z); a0[3] = (short)f2b(f0.w);
    a0[4] = (short)f2b(f1.x); a0[5] = (short)f2b(f1.y);
    a0[6] = (short)f2b(f1.z); a0[7] = (short)f2b(f1.w);
    a1[0] = (short)f2b(f2.x); a1[1] = (short)f2b(f2.y);
    a1[2] = (short)f2b(f2.z); a1[3] = (short)f2b(f2.w);
    a1[4] = (short)f2b(f3.x); a1[5] = (short)f2b(f3.y);
    a1[6] = (short)f2b(f3.z); a1[7] = (short)f2b(f3.w);

    f32x4 acc[8];
#pragma unroll
    for (int ns = 0; ns < 8; ++ns) acc[ns] = (f32x4){0.f, 0.f, 0.f, 0.f};
#pragma unroll
    for (int ns = 0; ns < 8; ++ns) {
        // fragment entries: e = (ns*8 + half*4 + quad)*16 + l16, 16B per lane
        const short8 b0 = *(const short8*)&Wf[((ns * 8 + 0 + quad) * 16 + l16) * 8];
        const short8 b1 = *(const short8*)&Wf[((ns * 8 + 4 + quad) * 16 + l16) * 8];
        acc[ns] = __builtin_amdgcn_mfma_f32_16x16x32_bf16(b0, a0, acc[ns], 0, 0, 0);
        acc[ns] = __builtin_amdgcn_mfma_f32_16x16x32_bf16(b1, a1, acc[ns], 0, 0, 0);
    }
    // D layout: col(l16)=table row, row(quad*4+j)=channel -> 8B stores
    unsigned short* op = UV + (size_t)row * 128 + quad * 4;
#pragma unroll
    for (int ns = 0; ns < 8; ++ns) {
        unsigned long long pk =
              (unsigned long long)f2b(acc[ns][0])
            | ((unsigned long long)f2b(acc[ns][1]) << 16)
            | ((unsigned long long)f2b(acc[ns][2]) << 32)
            | ((unsigned long long)f2b(acc[ns][3]) << 48);
        *(unsigned long long*)(op + ns * 16) = pk;
    }
}

// =====================================================================
// Phase 2: final[nn,d] = b[d] + max_{pp,to} ( U[r_to,d] + V[r_{t+1},d] )
// Paired-gather (one dword serves two row-gathers across wave halves),
// full 16-pp unroll. (R4 config — best measured remainder.)
// =====================================================================
__global__ __launch_bounds__(256) void gather_max(
        const int* __restrict__ path_input, const int* __restrict__ path_type,
        const unsigned int* __restrict__ UVu, const float* __restrict__ bias,
        float* __restrict__ out) {
    __shared__ int ridx[4][16][5];   // row * 64 (uint offsets)
    const int tid = threadIdx.x;
    const int nn0 = blockIdx.x * 4;
    for (int i = tid; i < 320; i += 256) {
        int ln = i / 80, j = i - ln * 80;
        int pp = j / 5, t = j - pp * 5;
        int nn = nn0 + ln;
        int g = nn >> 4, q = nn & 15;
        int addr = ((pp * 512 + g) * 16 + q) * 5 + t;
        ridx[ln][pp][t] = (path_type[t] * VOCAB + path_input[addr]) * 64;
    }
    __syncthreads();

    const int w = tid >> 6, lane = tid & 63;
    const int half = lane >> 5, l = lane & 31;
    const int nn = nn0 + w;

    float accLo = -1e30f, accHi = -1e30f;
#pragma unroll
    for (int pp = 0; pp < 16; ++pp) {
        int r0 = ridx[w][pp][0];
        int r1 = ridx[w][pp][1];
        int r2 = ridx[w][pp][2];
        int r3 = ridx[w][pp][3];
        int r4 = ridx[w][pp][4];
        unsigned int xa = UVu[(half ? r1 : r0) + l];          // {u0 | u1}
        unsigned int xb = UVu[(half ? r3 : r2) + l];          // {u2 | u3}
        unsigned int xc = UVu[(half ? r2 : r1) + 32 + l];     // {v1 | v2}
        unsigned int xd = UVu[(half ? r4 : r3) + 32 + l];     // {v3 | v4}
        float s1Lo = pkLo(xa) + pkLo(xc);
        float s1Hi = pkHi(xa) + pkHi(xc);
        float s2Lo = pkLo(xb) + pkLo(xd);
        float s2Hi = pkHi(xb) + pkHi(xd);
        accLo = fmaxf(accLo, fmaxf(s1Lo, s2Lo));
        accHi = fmaxf(accHi, fmaxf(s1Hi, s2Hi));
    }
    float oLo = fmaxf(accLo, __shfl_xor(accLo, 32));
    float oHi = fmaxf(accHi, __shfl_xor(accHi, 32));
    if (half == 0) {
        float2 bv = *(const float2*)(bias + 2 * l);
        float2 o;
        o.x = oLo + bv.x;
        o.y = oHi + bv.y;
        *(float2*)(out + (size_t)nn * 64 + 2 * l) = o;
    }
}

// =====================================================================
// Fallback (if workspace too small): direct fused fp32.
// =====================================================================
__global__ __launch_bounds__(64) void fused_direct(
        const int* __restrict__ path_input, const int* __restrict__ path_type,
        const float* __restrict__ tables, const float* __restrict__ convw,
        const float* __restrict__ bias, float* __restrict__ out) {
    const int nn = blockIdx.x;
    const int o = threadIdx.x;
    const int g = nn >> 4;
    const int q = nn & 15;
    float w0[64], w1[64];
#pragma unroll
    for (int i = 0; i < 64; ++i) {
        w0[i] = convw[o * 128 + i * 2];
        w1[i] = convw[o * 128 + i * 2 + 1];
    }
    int tb[5];
#pragma unroll
    for (int t = 0; t < 5; ++t) tb[t] = path_type[t] * VOCAB;
    __shared__ float emb[5][64];
    float acc = -1e30f;
    for (int pp = 0; pp < 16; ++pp) {
        int m = pp * 512 + g;
        const int* ip = path_input + ((m * 16 + q) * 5);
        __syncthreads();
#pragma unroll
        for (int t = 0; t < 5; ++t)
            emb[t][o] = tables[(size_t)(tb[t] + ip[t]) * 64 + o];
        __syncthreads();
#pragma unroll
        for (int to = 0; to < 4; ++to) {
            float s = 0.f;
#pragma unroll
            for (int i = 0; i < 64; ++i)
                s += w0[i] * emb[to][i] + w1[i] * emb[to + 1][i];
            acc = fmaxf(acc, s);
        }
    }
    out[(size_t)nn * 64 + o] = acc + bias[o];
}

extern "C" void kernel_launch(void* const* d_in, const int* in_sizes, int n_in,
                              void* d_out, int out_size, void* d_ws, size_t ws_size,
                              hipStream_t stream) {
    const int*   path_input = (const int*)d_in[0];
    const int*   path_type  = (const int*)d_in[1];
    const float* tables     = (const float*)d_in[2];
    const float* convw      = (const float*)d_in[3];
    const float* convb      = (const float*)d_in[4];
    float* out = (float*)d_out;

    const size_t needUV = (size_t)NROWS * 128 * sizeof(unsigned short); // 76.8 MB
    const size_t needWf = (size_t)16 * 1024 * sizeof(unsigned short);   // 32 KB
    if (ws_size >= needUV + needWf) {
        unsigned short* UV = (unsigned short*)d_ws;
        unsigned short* Wf = UV + (size_t)NROWS * 128;
        wprep<<<1, 256, 0, stream>>>(convw, Wf);
        transform_tables<<<(NTILES + 3) / 4, 256, 0, stream>>>(tables, Wf, UV);
        gather_max<<<OUTROWS / 4, 256, 0, stream>>>(path_input, path_type,
                                                    (const unsigned int*)UV, convb, out);
    } else {
        fused_direct<<<OUTROWS, 64, 0, stream>>>(path_input, path_type, tables, convw, convb, out);
    }
}

// Round 8
// 164.290 us; speedup vs baseline: 1.1413x; 1.0252x over previous
//
#include <hip/hip_runtime.h>
#include <hip/hip_bf16.h>

// Problem constants
#define B_  128
#define I_  64
#define P_  16
#define T_  5
#define NT  3
#define VOCAB 100000
#define D_  64
#define NROWS (NT * VOCAB)     // 300000
#define NPAIR (B_ * I_)        // 8192 (n)
#define OUTROWS NPAIR          // 8192 output rows of 64
#define NTILES (NROWS / 16)    // 18750

// ---------- bf16 helpers ----------
__device__ __forceinline__ float b2f(unsigned short h) {
    return __uint_as_float(((unsigned int)h) << 16);
}
__device__ __forceinline__ unsigned short f2b(float f) {
    unsigned int u = __float_as_uint(f);
    return (unsigned short)((u + 0x7fffu + ((u >> 16) & 1u)) >> 16);   // RNE
}
__device__ __forceinline__ float pkLo(unsigned int x) {      // low bf16 -> f32
    return __uint_as_float(x << 16);
}
__device__ __forceinline__ float pkHi(unsigned int x) {      // high bf16 -> f32
    return __uint_as_float(x & 0xffff0000u);
}

typedef short short8 __attribute__((ext_vector_type(8)));
typedef float f32x4 __attribute__((ext_vector_type(4)));

// =====================================================================
// wprep: write bf16 weight fragments to ws in EXACT mfma first-operand
// lane order. Entry e = ((cb*2+half)*4+quad)*16 + m holds 8 shorts:
//   channel c = cb*16+m, k = half*32 + quad*8 + j
// =====================================================================
__global__ __launch_bounds__(256) void wprep(
        const float* __restrict__ convw, unsigned short* __restrict__ Wf) {
    const int e0 = threadIdx.x * 4;
#pragma unroll
    for (int e = e0; e < e0 + 4; ++e) {
        int m = e & 15;
        int quad = (e >> 4) & 3;
        int half = (e >> 6) & 1;
        int cb = e >> 7;
        int c = cb * 16 + m;
        const float* wp = (c < 64) ? (convw + c * 128) : (convw + (c - 64) * 128 + 1);
#pragma unroll
        for (int j = 0; j < 8; ++j) {
            int k = half * 32 + quad * 8 + j;
            Wf[e * 8 + j] = f2b(wp[k * 2]);
        }
    }
}

// =====================================================================
// Phase 1: UV[r][c]: c<64 -> T[r,:]·W0[c,:] ; c>=64 -> T[r,:]·W1[c-64,:]
// Software-pipelined grid-stride: weight fragments HOISTED to registers
// (once per wave); tile k+1's 4 table loads issued before computing
// tile k -> s_waitcnt vmcnt(4), wave always has >=1KB in flight.
// LDS-free, barrier-free.
// =====================================================================
__global__ __launch_bounds__(256) void transform_tables(
        const float* __restrict__ tables, const unsigned short* __restrict__ Wf,
        unsigned short* __restrict__ UV) {
    const int tid = threadIdx.x;
    const int w = tid >> 6;
    const int lane = tid & 63;
    const int l16 = lane & 15;
    const int quad = lane >> 4;

    // ---- hoist all 16 weight fragments (L1-resident 16KB buffer) ----
    short8 WB0[8], WB1[8];
#pragma unroll
    for (int ns = 0; ns < 8; ++ns) {
        WB0[ns] = *(const short8*)&Wf[((ns * 8 + 0 + quad) * 16 + l16) * 8];
        WB1[ns] = *(const short8*)&Wf[((ns * 8 + 4 + quad) * 16 + l16) * 8];
    }

    const int NW = gridDim.x * 4;            // total waves
    int tile = blockIdx.x * 4 + w;
    if (tile >= NTILES) return;

    // prefetch tile 0
    float4 f0, f1, f2, f3;
    {
        const float* ap = tables + (size_t)(tile * 16 + l16) * 64 + quad * 8;
        f0 = *(const float4*)(ap);
        f1 = *(const float4*)(ap + 4);
        f2 = *(const float4*)(ap + 32);
        f3 = *(const float4*)(ap + 36);
    }

    while (true) {
        const int next = tile + NW;
        float4 g0, g1, g2, g3;
        if (next < NTILES) {
            const float* ap = tables + (size_t)(next * 16 + l16) * 64 + quad * 8;
            g0 = *(const float4*)(ap);
            g1 = *(const float4*)(ap + 4);
            g2 = *(const float4*)(ap + 32);
            g3 = *(const float4*)(ap + 36);
        }

        // ---- compute current tile from f* ----
        short8 a0, a1;
        a0[0] = (short)f2b(f0.x); a0[1] = (short)f2b(f0.y);
        a0[2] = (short)f2b(f0.z); a0[3] = (short)f2b(f0.w);
        a0[4] = (short)f2b(f1.x); a0[5] = (short)f2b(f1.y);
        a0[6] = (short)f2b(f1.z); a0[7] = (short)f2b(f1.w);
        a1[0] = (short)f2b(f2.x); a1[1] = (short)f2b(f2.y);
        a1[2] = (short)f2b(f2.z); a1[3] = (short)f2b(f2.w);
        a1[4] = (short)f2b(f3.x); a1[5] = (short)f2b(f3.y);
        a1[6] = (short)f2b(f3.z); a1[7] = (short)f2b(f3.w);

        f32x4 acc[8];
#pragma unroll
        for (int ns = 0; ns < 8; ++ns) acc[ns] = (f32x4){0.f, 0.f, 0.f, 0.f};
#pragma unroll
        for (int ns = 0; ns < 8; ++ns) {
            acc[ns] = __builtin_amdgcn_mfma_f32_16x16x32_bf16(WB0[ns], a0, acc[ns], 0, 0, 0);
            acc[ns] = __builtin_amdgcn_mfma_f32_16x16x32_bf16(WB1[ns], a1, acc[ns], 0, 0, 0);
        }
        // D layout: col(l16)=table row, row(quad*4+j)=channel -> 8B stores
        unsigned short* op = UV + (size_t)(tile * 16 + l16) * 128 + quad * 4;
#pragma unroll
        for (int ns = 0; ns < 8; ++ns) {
            unsigned long long pk =
                  (unsigned long long)f2b(acc[ns][0])
                | ((unsigned long long)f2b(acc[ns][1]) << 16)
                | ((unsigned long long)f2b(acc[ns][2]) << 32)
                | ((unsigned long long)f2b(acc[ns][3]) << 48);
            *(unsigned long long*)(op + ns * 16) = pk;
        }

        if (next >= NTILES) break;
        f0 = g0; f1 = g1; f2 = g2; f3 = g3;
        tile = next;
    }
}

// =====================================================================
// Phase 2: final[nn,d] = b[d] + max_{pp,to} ( U[r_to,d] + V[r_{t+1},d] )
// R5 split-wave variant (best measured remainder): each nn split across
// 2 waves (pp 0-7 / 8-15); paired-gather within each wave; LDS merge.
// Block = 256 thr = 4 waves = 2 nn. Grid 4096.
// =====================================================================
__global__ __launch_bounds__(256) void gather_max(
        const int* __restrict__ path_input, const int* __restrict__ path_type,
        const unsigned int* __restrict__ UVu, const float* __restrict__ bias,
        float* __restrict__ out) {
    __shared__ int ridx[2][16][5];        // row * 64 (uint offsets)
    __shared__ float part[2][2][64];      // [ln][pp-half][chan]
    const int tid = threadIdx.x;
    const int nn0 = blockIdx.x * 2;
    for (int i = tid; i < 160; i += 256) {
        int ln = i / 80, j = i - ln * 80;
        int pp = j / 5, t = j - pp * 5;
        int nn = nn0 + ln;
        int g = nn >> 4, q = nn & 15;
        int addr = ((pp * 512 + g) * 16 + q) * 5 + t;
        ridx[ln][pp][t] = (path_type[t] * VOCAB + path_input[addr]) * 64;
    }
    __syncthreads();

    const int w = tid >> 6;
    const int lane = tid & 63;
    const int half = lane >> 5, l = lane & 31;
    const int ln = w & 1;          // which nn
    const int ph = w >> 1;         // pp half

    float accLo = -1e30f, accHi = -1e30f;
#pragma unroll
    for (int k = 0; k < 8; ++k) {
        int pp = ph * 8 + k;
        int r0 = ridx[ln][pp][0];
        int r1 = ridx[ln][pp][1];
        int r2 = ridx[ln][pp][2];
        int r3 = ridx[ln][pp][3];
        int r4 = ridx[ln][pp][4];
        unsigned int xa = UVu[(half ? r1 : r0) + l];          // {u0 | u1}
        unsigned int xb = UVu[(half ? r3 : r2) + l];          // {u2 | u3}
        unsigned int xc = UVu[(half ? r2 : r1) + 32 + l];     // {v1 | v2}
        unsigned int xd = UVu[(half ? r4 : r3) + 32 + l];     // {v3 | v4}
        float s1Lo = pkLo(xa) + pkLo(xc);
        float s1Hi = pkHi(xa) + pkHi(xc);
        float s2Lo = pkLo(xb) + pkLo(xd);
        float s2Hi = pkHi(xb) + pkHi(xd);
        accLo = fmaxf(accLo, fmaxf(s1Lo, s2Lo));
        accHi = fmaxf(accHi, fmaxf(s1Hi, s2Hi));
    }
    float oLo = fmaxf(accLo, __shfl_xor(accLo, 32));
    float oHi = fmaxf(accHi, __shfl_xor(accHi, 32));
    if (half == 0) {
        part[ln][ph][2 * l]     = oLo;
        part[ln][ph][2 * l + 1] = oHi;
    }
    __syncthreads();
    if (tid < 128) {
        int oln = tid >> 6, c = tid & 63;
        float v = fmaxf(part[oln][0][c], part[oln][1][c]) + bias[c];
        out[(size_t)(nn0 + oln) * 64 + c] = v;
    }
}

// =====================================================================
// Fallback (if workspace too small): direct fused fp32.
// =====================================================================
__global__ __launch_bounds__(64) void fused_direct(
        const int* __restrict__ path_input, const int* __restrict__ path_type,
        const float* __restrict__ tables, const float* __restrict__ convw,
        const float* __restrict__ bias, float* __restrict__ out) {
    const int nn = blockIdx.x;
    const int o = threadIdx.x;
    const int g = nn >> 4;
    const int q = nn & 15;
    float w0[64], w1[64];
#pragma unroll
    for (int i = 0; i < 64; ++i) {
        w0[i] = convw[o * 128 + i * 2];
        w1[i] = convw[o * 128 + i * 2 + 1];
    }
    int tb[5];
#pragma unroll
    for (int t = 0; t < 5; ++t) tb[t] = path_type[t] * VOCAB;
    __shared__ float emb[5][64];
    float acc = -1e30f;
    for (int pp = 0; pp < 16; ++pp) {
        int m = pp * 512 + g;
        const int* ip = path_input + ((m * 16 + q) * 5);
        __syncthreads();
#pragma unroll
        for (int t = 0; t < 5; ++t)
            emb[t][o] = tables[(size_t)(tb[t] + ip[t]) * 64 + o];
        __syncthreads();
#pragma unroll
        for (int to = 0; to < 4; ++to) {
            float s = 0.f;
#pragma unroll
            for (int i = 0; i < 64; ++i)
                s += w0[i] * emb[to][i] + w1[i] * emb[to + 1][i];
            acc = fmaxf(acc, s);
        }
    }
    out[(size_t)nn * 64 + o] = acc + bias[o];
}

extern "C" void kernel_launch(void* const* d_in, const int* in_sizes, int n_in,
                              void* d_out, int out_size, void* d_ws, size_t ws_size,
                              hipStream_t stream) {
    const int*   path_input = (const int*)d_in[0];
    const int*   path_type  = (const int*)d_in[1];
    const float* tables     = (const float*)d_in[2];
    const float* convw      = (const float*)d_in[3];
    const float* convb      = (const float*)d_in[4];
    float* out = (float*)d_out;

    const size_t needUV = (size_t)NROWS * 128 * sizeof(unsigned short); // 76.8 MB
    const size_t needWf = (size_t)16 * 1024 * sizeof(unsigned short);   // 32 KB
    if (ws_size >= needUV + needWf) {
        unsigned short* UV = (unsigned short*)d_ws;
        unsigned short* Wf = UV + (size_t)NROWS * 128;
        wprep<<<1, 256, 0, stream>>>(convw, Wf);
        // 1024 blocks x 4 waves, grid-stride over 18750 tiles (~4.6 tiles/wave)
        transform_tables<<<1024, 256, 0, stream>>>(tables, Wf, UV);
        gather_max<<<OUTROWS / 2, 256, 0, stream>>>(path_input, path_type,
                                                    (const unsigned int*)UV, convb, out);
    } else {
        fused_direct<<<OUTROWS, 64, 0, stream>>>(path_input, path_type, tables, convw, convb, out);
    }
}

// Round 9
// 144.504 us; speedup vs baseline: 1.2975x; 1.1369x over previous
//
#include <hip/hip_runtime.h>
#include <hip/hip_bf16.h>

// Problem constants
#define B_  128
#define I_  64
#define P_  16
#define T_  5
#define NT  3
#define VOCAB 100000
#define D_  64
#define NPAIR (B_ * I_)        // 8192 (n)
#define OUTROWS NPAIR          // 8192 output rows of 64

// ---------- bf16 helpers ----------
__device__ __forceinline__ unsigned short f2b(float f) {
    unsigned int u = __float_as_uint(f);
    return (unsigned short)((u + 0x7fffu + ((u >> 16) & 1u)) >> 16);   // RNE
}

typedef short short8 __attribute__((ext_vector_type(8)));
typedef float f32x4 __attribute__((ext_vector_type(4)));

// =====================================================================
// wprep: bf16 weight fragments in EXACT mfma first-operand lane order.
// Entry e = ((cb*2+half)*4+quad)*16 + m holds 8 shorts (16B):
//   channel c = cb*16+m, k = half*32 + quad*8 + j
//   cb<4 -> W0[c][k] = convw[c*128 + 2k] ; cb>=4 -> W1[c-64][k] = convw[..+1]
// =====================================================================
__global__ __launch_bounds__(256) void wprep(
        const float* __restrict__ convw, unsigned short* __restrict__ Wf) {
    const int e0 = threadIdx.x * 4;
#pragma unroll
    for (int e = e0; e < e0 + 4; ++e) {
        int m = e & 15;
        int quad = (e >> 4) & 3;
        int half = (e >> 6) & 1;
        int cb = e >> 7;
        int c = cb * 16 + m;
        const float* wp = (c < 64) ? (convw + c * 128) : (convw + (c - 64) * 128 + 1);
#pragma unroll
        for (int j = 0; j < 8; ++j) {
            int k = half * 32 + quad * 8 + j;
            Wf[e * 8 + j] = f2b(wp[k * 2]);
        }
    }
}

// =====================================================================
// FUSED kernel: one wave per output row nn. Lane l16 = pp (the 16
// (m,q)=(pp*512+g, q) pairs feeding nn = the 16 B-operand columns).
// Per nn: gather 80 fp32 table rows (5 t x 16 pp, L3-resident), cvt to
// bf16 A-frags; for to in 0..3: U=W0*rows_to (ns 0..3 of Wf), V=W1*
// rows_{to+1} (ns 4..7), runmax = max(runmax, U+V) elementwise in
// D-layout (col=pp, row=channel). pp-max = 4-step shfl_xor over l16.
// No UV buffer, no atomics, no barriers, no LDS.
// =====================================================================
__global__ __launch_bounds__(256) void fused_path(
        const int* __restrict__ path_input, const int* __restrict__ path_type,
        const float* __restrict__ tables, const unsigned short* __restrict__ Wf,
        const float* __restrict__ bias, float* __restrict__ out) {
    const int tid = threadIdx.x;
    const int w = tid >> 6;
    const int lane = tid & 63;
    const int l16 = lane & 15;      // pp
    const int quad = lane >> 4;

    const int nn = blockIdx.x * 4 + w;
    const int g = nn >> 4, q = nn & 15;

    // ---- weight fragments (16KB buffer, L1/L2-resident) ----
    short8 WB0[8], WB1[8];
#pragma unroll
    for (int ns = 0; ns < 8; ++ns) {
        WB0[ns] = *(const short8*)&Wf[((ns * 8 + 0 + quad) * 16 + l16) * 8];
        WB1[ns] = *(const short8*)&Wf[((ns * 8 + 4 + quad) * 16 + l16) * 8];
    }

    // ---- row indices for my pp (=l16), all 5 timesteps ----
    int rows[5];
#pragma unroll
    for (int t = 0; t < 5; ++t) {
        int addr = ((l16 * 512 + g) * 16 + q) * 5 + t;
        rows[t] = path_type[t] * VOCAB + path_input[addr];
    }

    // ---- gather all 20 float4 chunks upfront (MLP) ----
    float4 F[20];
#pragma unroll
    for (int t = 0; t < 5; ++t) {
        const float* rp = tables + (size_t)rows[t] * 64;
        F[t * 4 + 0] = *(const float4*)(rp + quad * 8);
        F[t * 4 + 1] = *(const float4*)(rp + quad * 8 + 4);
        F[t * 4 + 2] = *(const float4*)(rp + 32 + quad * 8);
        F[t * 4 + 3] = *(const float4*)(rp + 32 + quad * 8 + 4);
    }

    // ---- convert to bf16 A-frags: A0[t] = k 0..31, A1[t] = k 32..63 ----
    short8 A0[5], A1[5];
#pragma unroll
    for (int t = 0; t < 5; ++t) {
        float4 fa = F[t * 4 + 0], fb = F[t * 4 + 1];
        float4 fc = F[t * 4 + 2], fd = F[t * 4 + 3];
        short8 a0, a1;
        a0[0] = (short)f2b(fa.x); a0[1] = (short)f2b(fa.y);
        a0[2] = (short)f2b(fa.z); a0[3] = (short)f2b(fa.w);
        a0[4] = (short)f2b(fb.x); a0[5] = (short)f2b(fb.y);
        a0[6] = (short)f2b(fb.z); a0[7] = (short)f2b(fb.w);
        a1[0] = (short)f2b(fc.x); a1[1] = (short)f2b(fc.y);
        a1[2] = (short)f2b(fc.z); a1[3] = (short)f2b(fc.w);
        a1[4] = (short)f2b(fd.x); a1[5] = (short)f2b(fd.y);
        a1[6] = (short)f2b(fd.z); a1[7] = (short)f2b(fd.w);
        A0[t] = a0; A1[t] = a1;
    }

    // ---- windows: runmax over to of U_to + V_{to+1} ----
    f32x4 runmax[4];
#pragma unroll
    for (int ns = 0; ns < 4; ++ns) runmax[ns] = (f32x4){-1e30f, -1e30f, -1e30f, -1e30f};
#pragma unroll
    for (int to = 0; to < 4; ++to) {
#pragma unroll
        for (int ns = 0; ns < 4; ++ns) {
            f32x4 uu = {0.f, 0.f, 0.f, 0.f};
            uu = __builtin_amdgcn_mfma_f32_16x16x32_bf16(WB0[ns], A0[to], uu, 0, 0, 0);
            uu = __builtin_amdgcn_mfma_f32_16x16x32_bf16(WB1[ns], A1[to], uu, 0, 0, 0);
            f32x4 vv = {0.f, 0.f, 0.f, 0.f};
            vv = __builtin_amdgcn_mfma_f32_16x16x32_bf16(WB0[ns + 4], A0[to + 1], vv, 0, 0, 0);
            vv = __builtin_amdgcn_mfma_f32_16x16x32_bf16(WB1[ns + 4], A1[to + 1], vv, 0, 0, 0);
#pragma unroll
            for (int j = 0; j < 4; ++j)
                runmax[ns][j] = fmaxf(runmax[ns][j], uu[j] + vv[j]);
        }
    }

    // ---- max over pp = max over the 16 D-columns (lanes l16) ----
#pragma unroll
    for (int ns = 0; ns < 4; ++ns) {
#pragma unroll
        for (int j = 0; j < 4; ++j) {
            float v = runmax[ns][j];
            v = fmaxf(v, __shfl_xor(v, 1));
            v = fmaxf(v, __shfl_xor(v, 2));
            v = fmaxf(v, __shfl_xor(v, 4));
            v = fmaxf(v, __shfl_xor(v, 8));
            runmax[ns][j] = v;
        }
    }
    if (l16 == 0) {
        // lane (0, quad) holds channels ns*16 + quad*4 + j
#pragma unroll
        for (int ns = 0; ns < 4; ++ns) {
            int c = ns * 16 + quad * 4;
            float4 bv = *(const float4*)(bias + c);
            float4 o;
            o.x = runmax[ns][0] + bv.x;
            o.y = runmax[ns][1] + bv.y;
            o.z = runmax[ns][2] + bv.z;
            o.w = runmax[ns][3] + bv.w;
            *(float4*)(out + (size_t)nn * 64 + c) = o;
        }
    }
}

// =====================================================================
// Fallback (if workspace too small): direct fused fp32.
// =====================================================================
__global__ __launch_bounds__(64) void fused_direct(
        const int* __restrict__ path_input, const int* __restrict__ path_type,
        const float* __restrict__ tables, const float* __restrict__ convw,
        const float* __restrict__ bias, float* __restrict__ out) {
    const int nn = blockIdx.x;
    const int o = threadIdx.x;
    const int g = nn >> 4;
    const int q = nn & 15;
    float w0[64], w1[64];
#pragma unroll
    for (int i = 0; i < 64; ++i) {
        w0[i] = convw[o * 128 + i * 2];
        w1[i] = convw[o * 128 + i * 2 + 1];
    }
    int tb[5];
#pragma unroll
    for (int t = 0; t < 5; ++t) tb[t] = path_type[t] * VOCAB;
    __shared__ float emb[5][64];
    float acc = -1e30f;
    for (int pp = 0; pp < 16; ++pp) {
        int m = pp * 512 + g;
        const int* ip = path_input + ((m * 16 + q) * 5);
        __syncthreads();
#pragma unroll
        for (int t = 0; t < 5; ++t)
            emb[t][o] = tables[(size_t)(tb[t] + ip[t]) * 64 + o];
        __syncthreads();
#pragma unroll
        for (int to = 0; to < 4; ++to) {
            float s = 0.f;
#pragma unroll
            for (int i = 0; i < 64; ++i)
                s += w0[i] * emb[to][i] + w1[i] * emb[to + 1][i];
            acc = fmaxf(acc, s);
        }
    }
    out[(size_t)nn * 64 + o] = acc + bias[o];
}

extern "C" void kernel_launch(void* const* d_in, const int* in_sizes, int n_in,
                              void* d_out, int out_size, void* d_ws, size_t ws_size,
                              hipStream_t stream) {
    const int*   path_input = (const int*)d_in[0];
    const int*   path_type  = (const int*)d_in[1];
    const float* tables     = (const float*)d_in[2];
    const float* convw      = (const float*)d_in[3];
    const float* convb      = (const float*)d_in[4];
    float* out = (float*)d_out;

    const size_t needWf = (size_t)16 * 1024 * sizeof(unsigned short);   // 32 KB
    if (ws_size >= needWf) {
        unsigned short* Wf = (unsigned short*)d_ws;
        wprep<<<1, 256, 0, stream>>>(convw, Wf);
        fused_path<<<OUTROWS / 4, 256, 0, stream>>>(path_input, path_type,
                                                    tables, Wf, convb, out);
    } else {
        fused_direct<<<OUTROWS, 64, 0, stream>>>(path_input, path_type, tables, convw, convb, out);
    }
}

// Round 10
// 132.774 us; speedup vs baseline: 1.4122x; 1.0883x over previous
//
#include <hip/hip_runtime.h>
#include <hip/hip_bf16.h>

// Problem constants
#define B_  128
#define I_  64
#define P_  16
#define T_  5
#define NT  3
#define VOCAB 100000
#define D_  64
#define NPAIR (B_ * I_)        // 8192 (n)
#define OUTROWS NPAIR          // 8192 output rows of 64

// ---------- bf16 helpers ----------
__device__ __forceinline__ unsigned short f2b(float f) {
    unsigned int u = __float_as_uint(f);
    return (unsigned short)((u + 0x7fffu + ((u >> 16) & 1u)) >> 16);   // RNE
}

typedef short short8 __attribute__((ext_vector_type(8)));
typedef float f32x4 __attribute__((ext_vector_type(4)));

#define AROW_STRIDE 160        // bf16 row stride in LDS bytes (16B-aligned)
#define AWAVE_BYTES (80 * AROW_STRIDE)   // 12800 per wave

// =====================================================================
// wprep: bf16 weight fragments in EXACT mfma first-operand lane order.
// Entry e = ((cb*2+half)*4+quad)*16 + m holds 8 shorts (16B):
//   channel c = cb*16+m, k = half*32 + quad*8 + j
//   cb<4 -> W0[c][k] = convw[c*128 + 2k] ; cb>=4 -> W1[c-64][k] = convw[..+1]
// =====================================================================
__global__ __launch_bounds__(256) void wprep(
        const float* __restrict__ convw, unsigned short* __restrict__ Wf) {
    const int e0 = threadIdx.x * 4;
#pragma unroll
    for (int e = e0; e < e0 + 4; ++e) {
        int m = e & 15;
        int quad = (e >> 4) & 3;
        int half = (e >> 6) & 1;
        int cb = e >> 7;
        int c = cb * 16 + m;
        const float* wp = (c < 64) ? (convw + c * 128) : (convw + (c - 64) * 128 + 1);
#pragma unroll
        for (int j = 0; j < 8; ++j) {
            int k = half * 32 + quad * 8 + j;
            Wf[e * 8 + j] = f2b(wp[k * 2]);
        }
    }
}

// =====================================================================
// FUSED kernel, dense-gather edition. One wave per output row nn.
// Gather phase: instruction i reads 4 rows FULLY CONTIGUOUSLY:
//   lane (r2=lane>>4, c16=lane&15) reads row (t=i>>2, pp=(i&3)*4+r2),
//   bytes [c16*16, +16)  -> 8 fully-used 128B segments per instruction
//   (vs 32 sparse segments in the fragment-layout gather).
// Rows converted to bf16 and staged in per-wave LDS (no barriers: each
// wave reads only its own region), then ds_read_b128 yields the MFMA
// A-fragments. Compute/reduce identical to verified R8 kernel.
// =====================================================================
__global__ __launch_bounds__(256) void fused_path(
        const int* __restrict__ path_input, const int* __restrict__ path_type,
        const float* __restrict__ tables, const unsigned short* __restrict__ Wf,
        const float* __restrict__ bias, float* __restrict__ out) {
    __shared__ __align__(16) unsigned char Asmem[4][AWAVE_BYTES];   // 51200 B
    const int tid = threadIdx.x;
    const int w = tid >> 6;
    const int lane = tid & 63;
    const int l16 = lane & 15;      // pp (compute phase) / c16 (gather phase)
    const int quad = lane >> 4;
    const int r2 = lane >> 4;       // row-within-group (gather phase): 0..3
    const int c16 = lane & 15;      // 16B chunk within row (gather phase)

    const int nn = blockIdx.x * 4 + w;
    const int g = nn >> 4, q = nn & 15;
    unsigned char* myA = Asmem[w];

    // ---- weight fragments (16KB buffer, L1/L2-resident) ----
    short8 WB0[8], WB1[8];
#pragma unroll
    for (int ns = 0; ns < 8; ++ns) {
        WB0[ns] = *(const short8*)&Wf[((ns * 8 + 0 + quad) * 16 + l16) * 8];
        WB1[ns] = *(const short8*)&Wf[((ns * 8 + 4 + quad) * 16 + l16) * 8];
    }

    // ---- per-instruction row indices (broadcast over c16: 1 segment each) ----
    int roff[20];   // row element offset = rowid * 64
#pragma unroll
    for (int i = 0; i < 20; ++i) {
        int t = i >> 2, sub = i & 3;
        int pp = sub * 4 + r2;
        int addr = ((pp * 512 + g) * 16 + q) * 5 + t;
        roff[i] = (path_type[t] * VOCAB + path_input[addr]) * 64;
    }

    // ---- dense gathers: 16B contiguous per lane, 4 full rows per instr ----
    float4 F[20];
#pragma unroll
    for (int i = 0; i < 20; ++i)
        F[i] = *(const float4*)(tables + (size_t)roff[i] + c16 * 4);

    // ---- convert + stage to LDS (bf16, per-wave region, no barrier) ----
#pragma unroll
    for (int i = 0; i < 20; ++i) {
        int t = i >> 2, sub = i & 3;
        int R = t * 16 + sub * 4 + r2;
        unsigned int p0 = (unsigned int)f2b(F[i].x) | ((unsigned int)f2b(F[i].y) << 16);
        unsigned int p1 = (unsigned int)f2b(F[i].z) | ((unsigned int)f2b(F[i].w) << 16);
        uint2 pk; pk.x = p0; pk.y = p1;
        *(uint2*)(myA + R * AROW_STRIDE + c16 * 8) = pk;
    }

    // ---- read MFMA A-fragments: lane (l16,quad), k = [half*32 + quad*8 + j) ----
    short8 A0[5], A1[5];
#pragma unroll
    for (int t = 0; t < 5; ++t) {
        const unsigned char* rp = myA + (t * 16 + l16) * AROW_STRIDE;
        A0[t] = *(const short8*)(rp + quad * 16);          // bf16 k 0..31
        A1[t] = *(const short8*)(rp + 64 + quad * 16);     // bf16 k 32..63
    }

    // ---- windows: runmax over to of U_to + V_{to+1} ----
    f32x4 runmax[4];
#pragma unroll
    for (int ns = 0; ns < 4; ++ns) runmax[ns] = (f32x4){-1e30f, -1e30f, -1e30f, -1e30f};
#pragma unroll
    for (int to = 0; to < 4; ++to) {
#pragma unroll
        for (int ns = 0; ns < 4; ++ns) {
            f32x4 uu = {0.f, 0.f, 0.f, 0.f};
            uu = __builtin_amdgcn_mfma_f32_16x16x32_bf16(WB0[ns], A0[to], uu, 0, 0, 0);
            uu = __builtin_amdgcn_mfma_f32_16x16x32_bf16(WB1[ns], A1[to], uu, 0, 0, 0);
            f32x4 vv = {0.f, 0.f, 0.f, 0.f};
            vv = __builtin_amdgcn_mfma_f32_16x16x32_bf16(WB0[ns + 4], A0[to + 1], vv, 0, 0, 0);
            vv = __builtin_amdgcn_mfma_f32_16x16x32_bf16(WB1[ns + 4], A1[to + 1], vv, 0, 0, 0);
#pragma unroll
            for (int j = 0; j < 4; ++j)
                runmax[ns][j] = fmaxf(runmax[ns][j], uu[j] + vv[j]);
        }
    }

    // ---- max over pp = max over the 16 D-columns (lanes l16) ----
#pragma unroll
    for (int ns = 0; ns < 4; ++ns) {
#pragma unroll
        for (int j = 0; j < 4; ++j) {
            float v = runmax[ns][j];
            v = fmaxf(v, __shfl_xor(v, 1));
            v = fmaxf(v, __shfl_xor(v, 2));
            v = fmaxf(v, __shfl_xor(v, 4));
            v = fmaxf(v, __shfl_xor(v, 8));
            runmax[ns][j] = v;
        }
    }
    if (l16 == 0) {
        // lane (0, quad) holds channels ns*16 + quad*4 + j
#pragma unroll
        for (int ns = 0; ns < 4; ++ns) {
            int c = ns * 16 + quad * 4;
            float4 bv = *(const float4*)(bias + c);
            float4 o;
            o.x = runmax[ns][0] + bv.x;
            o.y = runmax[ns][1] + bv.y;
            o.z = runmax[ns][2] + bv.z;
            o.w = runmax[ns][3] + bv.w;
            *(float4*)(out + (size_t)nn * 64 + c) = o;
        }
    }
}

// =====================================================================
// Fallback (if workspace too small): direct fused fp32.
// =====================================================================
__global__ __launch_bounds__(64) void fused_direct(
        const int* __restrict__ path_input, const int* __restrict__ path_type,
        const float* __restrict__ tables, const float* __restrict__ convw,
        const float* __restrict__ bias, float* __restrict__ out) {
    const int nn = blockIdx.x;
    const int o = threadIdx.x;
    const int g = nn >> 4;
    const int q = nn & 15;
    float w0[64], w1[64];
#pragma unroll
    for (int i = 0; i < 64; ++i) {
        w0[i] = convw[o * 128 + i * 2];
        w1[i] = convw[o * 128 + i * 2 + 1];
    }
    int tb[5];
#pragma unroll
    for (int t = 0; t < 5; ++t) tb[t] = path_type[t] * VOCAB;
    __shared__ float emb[5][64];
    float acc = -1e30f;
    for (int pp = 0; pp < 16; ++pp) {
        int m = pp * 512 + g;
        const int* ip = path_input + ((m * 16 + q) * 5);
        __syncthreads();
#pragma unroll
        for (int t = 0; t < 5; ++t)
            emb[t][o] = tables[(size_t)(tb[t] + ip[t]) * 64 + o];
        __syncthreads();
#pragma unroll
        for (int to = 0; to < 4; ++to) {
            float s = 0.f;
#pragma unroll
            for (int i = 0; i < 64; ++i)
                s += w0[i] * emb[to][i] + w1[i] * emb[to + 1][i];
            acc = fmaxf(acc, s);
        }
    }
    out[(size_t)nn * 64 + o] = acc + bias[o];
}

extern "C" void kernel_launch(void* const* d_in, const int* in_sizes, int n_in,
                              void* d_out, int out_size, void* d_ws, size_t ws_size,
                              hipStream_t stream) {
    const int*   path_input = (const int*)d_in[0];
    const int*   path_type  = (const int*)d_in[1];
    const float* tables     = (const float*)d_in[2];
    const float* convw      = (const float*)d_in[3];
    const float* convb      = (const float*)d_in[4];
    float* out = (float*)d_out;

    const size_t needWf = (size_t)16 * 1024 * sizeof(unsigned short);   // 32 KB
    if (ws_size >= needWf) {
        unsigned short* Wf = (unsigned short*)d_ws;
        wprep<<<1, 256, 0, stream>>>(convw, Wf);
        fused_path<<<OUTROWS / 4, 256, 0, stream>>>(path_input, path_type,
                                                    tables, Wf, convb, out);
    } else {
        fused_direct<<<OUTROWS, 64, 0, stream>>>(path_input, path_type, tables, convw, convb, out);
    }
}